// Round 1
// baseline (935.020 us; speedup 1.0000x reference)
//
#include <hip/hip_runtime.h>
#include <hip/hip_bf16.h>

#define T_TOK 4096
#define HDIM  2048
#define NEXP  64
#define IDIM  768
#define TOPK  4
#define CAPE  512
#define NFLAT (T_TOK*TOPK)

typedef __bf16        bf16x8 __attribute__((ext_vector_type(8)));
typedef float         f32x4  __attribute__((ext_vector_type(4)));
typedef unsigned int  u32x4  __attribute__((ext_vector_type(4)));

__device__ __forceinline__ unsigned short f2bf(float f) {
  unsigned u = __builtin_bit_cast(unsigned, f);
  u = u + 0x7FFFu + ((u >> 16) & 1u);
  return (unsigned short)(u >> 16);
}
__device__ __forceinline__ unsigned pack2(float lo, float hi) {
  return (unsigned)f2bf(lo) | ((unsigned)f2bf(hi) << 16);
}

// ---------------- gating: logits, top-4, renorm weights; also hs -> bf16 ----------------
__global__ __launch_bounds__(256) void k_gating(
    const float* __restrict__ hs, const float* __restrict__ gw,
    unsigned short* __restrict__ hs_bf, int* __restrict__ tidx, float* __restrict__ tw)
{
  __shared__ float lg[16][64];
  const int tid = threadIdx.x;
  const int t0  = blockIdx.x * 16;

  // phase A: bf16 conversion of these 16 rows
  {
    const f32x4* src = (const f32x4*)(hs + (size_t)t0 * HDIM);
    for (int i = tid; i < 16 * HDIM / 4; i += 256) {
      f32x4 v = src[i];
      ushort4 o;
      o.x = f2bf(v[0]); o.y = f2bf(v[1]); o.z = f2bf(v[2]); o.w = f2bf(v[3]);
      *(ushort4*)(hs_bf + (size_t)t0 * HDIM + (size_t)i * 4) = o;
    }
  }

  // phase B: logits.  lane = expert, each wave handles 4 tokens.
  const int lane = tid & 63, wv = tid >> 6;
  {
    const f32x4* gr = (const f32x4*)(gw + (size_t)lane * HDIM);
    const f32x4* x0 = (const f32x4*)(hs + (size_t)(t0 + wv*4 + 0) * HDIM);
    const f32x4* x1 = (const f32x4*)(hs + (size_t)(t0 + wv*4 + 1) * HDIM);
    const f32x4* x2 = (const f32x4*)(hs + (size_t)(t0 + wv*4 + 2) * HDIM);
    const f32x4* x3 = (const f32x4*)(hs + (size_t)(t0 + wv*4 + 3) * HDIM);
    float a0=0.f, a1=0.f, a2=0.f, a3=0.f;
    for (int h = 0; h < HDIM/4; ++h) {
      f32x4 g = gr[h];
      f32x4 v0 = x0[h], v1 = x1[h], v2 = x2[h], v3 = x3[h];
      a0 += g[0]*v0[0] + g[1]*v0[1] + g[2]*v0[2] + g[3]*v0[3];
      a1 += g[0]*v1[0] + g[1]*v1[1] + g[2]*v1[2] + g[3]*v1[3];
      a2 += g[0]*v2[0] + g[1]*v2[1] + g[2]*v2[2] + g[3]*v2[3];
      a3 += g[0]*v3[0] + g[1]*v3[1] + g[2]*v3[2] + g[3]*v3[3];
    }
    lg[wv*4+0][lane] = a0;
    lg[wv*4+1][lane] = a1;
    lg[wv*4+2][lane] = a2;
    lg[wv*4+3][lane] = a3;
  }
  __syncthreads();

  // phase C: per-token top-4 (stable: strict >, lowest index wins) + softmax over selected
  if (tid < 16) {
    const int t = t0 + tid;
    unsigned long long chosen = 0ull;
    float bv[4]; int bi[4];
#pragma unroll
    for (int k = 0; k < 4; ++k) {
      float best = -1e30f; int b = 0;
      for (int e = 0; e < 64; ++e) {
        float v = lg[tid][e];
        if (!((chosen >> e) & 1ull) && v > best) { best = v; b = e; }
      }
      chosen |= 1ull << b; bv[k] = best; bi[k] = b;
    }
    float s = 0.f, w[4];
#pragma unroll
    for (int k = 0; k < 4; ++k) { w[k] = __expf(bv[k] - bv[0]); s += w[k]; }
    float inv = 1.f / s;
#pragma unroll
    for (int k = 0; k < 4; ++k) { tidx[t*4+k] = bi[k]; tw[t*4+k] = w[k] * inv; }
  }
}

// ---------------- per-expert stable rank (ballot scan) ----------------
__global__ __launch_bounds__(64) void k_count_rank(
    const int* __restrict__ tidx, int* __restrict__ rankb, int* __restrict__ counts)
{
  const int e = blockIdx.x;
  const int lane = threadIdx.x;
  int base = 0;
  for (int c = 0; c < NFLAT/64; ++c) {
    int n = c*64 + lane;
    bool m = (tidx[n] == e);
    unsigned long long mask = __ballot(m);
    if (m) rankb[n] = base + __popcll(mask & ((1ull << lane) - 1ull));
    base += __popcll(mask);
  }
  if (lane == 0) counts[e] = base;
}

// ---------------- starts scan + sorted-row maps ----------------
__global__ __launch_bounds__(256) void k_build(
    const int* __restrict__ tidx, const float* __restrict__ tw,
    const int* __restrict__ rankb, const int* __restrict__ counts,
    int* __restrict__ starts, int* __restrict__ row_info, float* __restrict__ w_row)
{
  __shared__ int s_starts[NEXP];
  if (threadIdx.x == 0) {
    int s = 0;
    for (int e = 0; e < NEXP; ++e) { s_starts[e] = s; starts[e] = s; s += counts[e]; }
  }
  __syncthreads();
  for (int n = threadIdx.x; n < NFLAT; n += 256) {
    int e = tidx[n], r = rankb[n];
    int sr = s_starts[e] + r;           // unique per n, in [0, NFLAT)
    row_info[sr] = n;
    w_row[sr]   = (r < CAPE) ? tw[n] : 0.f;   // dropped rows contribute 0
  }
}

// ---------------- GEMM1 (gather A) + fused SwiGLU -> a_buf (bf16) ----------------
// block tile: 128 rows x 128 i-cols, computing BOTH g and u halves.
__global__ __launch_bounds__(256, 2) void k_gemm1(
    const unsigned short* __restrict__ hs_bf, const float* __restrict__ w13,
    const int* __restrict__ counts, const int* __restrict__ starts,
    const int* __restrict__ row_info, unsigned short* __restrict__ a_buf)
{
  const int nt = blockIdx.x;   // 0..5   (128 i-cols each)
  const int mt = blockIdx.y;   // 0..3
  const int e  = blockIdx.z;   // 0..63
  const int count = min(counts[e], CAPE);
  const int R0 = mt * 128;
  if (R0 >= count) return;
  const int tid = threadIdx.x;
  const int base_sorted = starts[e] + R0;

  __shared__ __align__(16) char lds[3*16384];
  char* Alds = lds;             // [128 m][8 chunks of 16B], chunk xor-swizzled by (m&7)
  char* Bgl  = lds + 16384;    // [128 n][8 chunks], k-pair packed u32, swizzle (n&7)
  char* Bul  = lds + 32768;

  const int mrow = tid >> 3, cchunk = tid & 7;   // A staging coords
  int tokp[4];
#pragma unroll
  for (int p = 0; p < 4; ++p) {
    int sr = base_sorted + mrow + p*32;
    if (sr > NFLAT-1) sr = NFLAT-1;
    tokp[p] = row_info[sr] >> 2;
  }
  const float* w13e = w13 + (size_t)e * HDIM * (2*IDIM);
  const int kg = tid >> 5;          // 0..7  (k-group of 8)
  const int n4 = (tid & 31) * 4;    // 0..124

  const int lane = tid & 63, wv = tid >> 6;
  const int wr = wv >> 1, wc = wv & 1;

  f32x4 accg[4][4], accu[4][4];
#pragma unroll
  for (int i = 0; i < 4; ++i)
#pragma unroll
    for (int j = 0; j < 4; ++j) { accg[i][j] = f32x4{0.f,0.f,0.f,0.f}; accu[i][j] = f32x4{0.f,0.f,0.f,0.f}; }

  for (int kt = 0; kt < HDIM/64; ++kt) {
    // stage A (bf16 rows gathered by token)
#pragma unroll
    for (int p = 0; p < 4; ++p) {
      int m = mrow + p*32;
      u32x4 v = *(const u32x4*)(hs_bf + (size_t)tokp[p]*HDIM + kt*64 + cchunk*8);
      *(u32x4*)(Alds + m*128 + ((cchunk ^ (m & 7)) << 4)) = v;
    }
    // stage B: g half and u half, f32 -> bf16 k-pair packed
#pragma unroll
    for (int half = 0; half < 2; ++half) {
      const float* bp = w13e + (size_t)(kt*64 + kg*8) * (2*IDIM) + half*IDIM + nt*128 + n4;
      f32x4 f[8];
#pragma unroll
      for (int j = 0; j < 8; ++j) f[j] = *(const f32x4*)(bp + (size_t)j * (2*IDIM));
      char* Bl = half ? Bul : Bgl;
#pragma unroll
      for (int i = 0; i < 4; ++i) {
        int n = n4 + i;
        u32x4 q;
        q[0] = pack2(f[0][i], f[1][i]);
        q[1] = pack2(f[2][i], f[3][i]);
        q[2] = pack2(f[4][i], f[5][i]);
        q[3] = pack2(f[6][i], f[7][i]);
        *(u32x4*)(Bl + n*128 + ((kg ^ (n & 7)) << 4)) = q;
      }
    }
    __syncthreads();
    // compute
#pragma unroll
    for (int kfi = 0; kfi < 2; ++kfi) {
      bf16x8 af[4], bg[4], bu[4];
#pragma unroll
      for (int mi = 0; mi < 4; ++mi) {
        int row = wr*64 + mi*16 + (lane & 15);
        af[mi] = *(const bf16x8*)(Alds + row*128 + ((((kfi<<2)|(lane>>4)) ^ (row & 7)) << 4));
      }
#pragma unroll
      for (int ni = 0; ni < 4; ++ni) {
        int n = wc*64 + ni*16 + (lane & 15);
        int c = (((kfi<<2)|(lane>>4)) ^ (n & 7)) << 4;
        bg[ni] = *(const bf16x8*)(Bgl + n*128 + c);
        bu[ni] = *(const bf16x8*)(Bul + n*128 + c);
      }
#pragma unroll
      for (int mi = 0; mi < 4; ++mi)
#pragma unroll
        for (int ni = 0; ni < 4; ++ni) {
          accg[mi][ni] = __builtin_amdgcn_mfma_f32_16x16x32_bf16(af[mi], bg[ni], accg[mi][ni], 0, 0, 0);
          accu[mi][ni] = __builtin_amdgcn_mfma_f32_16x16x32_bf16(af[mi], bu[ni], accu[mi][ni], 0, 0, 0);
        }
    }
    __syncthreads();
  }

  // epilogue: silu(g)*u -> a_buf (bf16), rows are sorted-contiguous
#pragma unroll
  for (int mi = 0; mi < 4; ++mi) {
#pragma unroll
    for (int j = 0; j < 4; ++j) {
      int rl = wr*64 + mi*16 + (lane >> 4)*4 + j;
      if (R0 + rl < count) {
        size_t rowoff = (size_t)(base_sorted + rl) * IDIM;
#pragma unroll
        for (int ni = 0; ni < 4; ++ni) {
          int col = nt*128 + wc*64 + ni*16 + (lane & 15);
          float g = accg[mi][ni][j], u = accu[mi][ni][j];
          float a = (g / (1.f + __expf(-g))) * u;
          a_buf[rowoff + col] = f2bf(a);
        }
      }
    }
  }
}

// ---------------- GEMM2 + weighted atomic scatter into out ----------------
// block tile: 128 rows x 256 cols of H
__global__ __launch_bounds__(256, 2) void k_gemm2(
    const unsigned short* __restrict__ a_buf, const float* __restrict__ w2,
    const int* __restrict__ counts, const int* __restrict__ starts,
    const int* __restrict__ row_info, const float* __restrict__ w_row,
    float* __restrict__ out)
{
  const int nt = blockIdx.x;   // 0..7  (256 cols each)
  const int mt = blockIdx.y;   // 0..3
  const int e  = blockIdx.z;   // 0..63
  const int count = min(counts[e], CAPE);
  const int R0 = mt * 128;
  if (R0 >= count) return;
  const int tid = threadIdx.x;
  const int base_sorted = starts[e] + R0;

  __shared__ __align__(16) char lds[16384 + 32768];
  char* Alds = lds;            // [128 m][8 chunks]
  char* Blds = lds + 16384;    // [256 n][8 chunks]

  const int mrow = tid >> 3, cchunk = tid & 7;
  int srp[4];
#pragma unroll
  for (int p = 0; p < 4; ++p) {
    int sr = base_sorted + mrow + p*32;
    srp[p] = (sr > NFLAT-1) ? (NFLAT-1) : sr;
  }
  const float* w2e = w2 + (size_t)e * IDIM * HDIM;
  const int kg = tid >> 5, n4 = (tid & 31) * 4;
  const int lane = tid & 63, wv = tid >> 6, wr = wv >> 1, wc = wv & 1;

  f32x4 acc[4][8];
#pragma unroll
  for (int i = 0; i < 4; ++i)
#pragma unroll
    for (int j = 0; j < 8; ++j) acc[i][j] = f32x4{0.f,0.f,0.f,0.f};

  for (int kt = 0; kt < IDIM/64; ++kt) {
    // stage A from a_buf (already bf16, rows contiguous in sorted space)
#pragma unroll
    for (int p = 0; p < 4; ++p) {
      int m = mrow + p*32;
      u32x4 v = *(const u32x4*)(a_buf + (size_t)srp[p]*IDIM + kt*64 + cchunk*8);
      *(u32x4*)(Alds + m*128 + ((cchunk ^ (m & 7)) << 4)) = v;
    }
    // stage B: 256 cols in two passes
#pragma unroll
    for (int pass = 0; pass < 2; ++pass) {
      int nn = n4 + pass*128;
      const float* bp = w2e + (size_t)(kt*64 + kg*8) * HDIM + nt*256 + nn;
      f32x4 f[8];
#pragma unroll
      for (int j = 0; j < 8; ++j) f[j] = *(const f32x4*)(bp + (size_t)j * HDIM);
#pragma unroll
      for (int i = 0; i < 4; ++i) {
        int n = nn + i;
        u32x4 q;
        q[0] = pack2(f[0][i], f[1][i]);
        q[1] = pack2(f[2][i], f[3][i]);
        q[2] = pack2(f[4][i], f[5][i]);
        q[3] = pack2(f[6][i], f[7][i]);
        *(u32x4*)(Blds + n*128 + ((kg ^ (n & 7)) << 4)) = q;
      }
    }
    __syncthreads();
#pragma unroll
    for (int kfi = 0; kfi < 2; ++kfi) {
      bf16x8 af[4], bb[8];
#pragma unroll
      for (int mi = 0; mi < 4; ++mi) {
        int row = wr*64 + mi*16 + (lane & 15);
        af[mi] = *(const bf16x8*)(Alds + row*128 + ((((kfi<<2)|(lane>>4)) ^ (row & 7)) << 4));
      }
#pragma unroll
      for (int ni = 0; ni < 8; ++ni) {
        int n = wc*128 + ni*16 + (lane & 15);
        bb[ni] = *(const bf16x8*)(Blds + n*128 + (((((kfi<<2)|(lane>>4)) ^ (n & 7))) << 4));
      }
#pragma unroll
      for (int mi = 0; mi < 4; ++mi)
#pragma unroll
        for (int ni = 0; ni < 8; ++ni)
          acc[mi][ni] = __builtin_amdgcn_mfma_f32_16x16x32_bf16(af[mi], bb[ni], acc[mi][ni], 0, 0, 0);
    }
    __syncthreads();
  }

  // epilogue: out[t] += w * y  (atomic f32)
#pragma unroll
  for (int mi = 0; mi < 4; ++mi) {
#pragma unroll
    for (int j = 0; j < 4; ++j) {
      int rl = wr*64 + mi*16 + (lane >> 4)*4 + j;
      if (R0 + rl < count) {
        int sr = base_sorted + rl;
        int info = row_info[sr];
        int t = info >> 2;
        float wgt = w_row[sr];
        float* orow = out + (size_t)t * HDIM;
#pragma unroll
        for (int ni = 0; ni < 8; ++ni) {
          int col = nt*256 + wc*128 + ni*16 + (lane & 15);
          atomicAdd(orow + col, wgt * acc[mi][ni][j]);
        }
      }
    }
  }
}

extern "C" void kernel_launch(void* const* d_in, const int* in_sizes, int n_in,
                              void* d_out, int out_size, void* d_ws, size_t ws_size,
                              hipStream_t stream) {
  const float* hs  = (const float*)d_in[0];
  const float* gw  = (const float*)d_in[1];
  const float* w13 = (const float*)d_in[2];
  const float* w2  = (const float*)d_in[3];
  float* out = (float*)d_out;

  char* ws = (char*)d_ws;
  size_t off = 0;
  auto alloc = [&](size_t bytes) {
    off = (off + 255) & ~(size_t)255;
    char* p = ws + off;
    off += bytes;
    return p;
  };
  unsigned short* hs_bf = (unsigned short*)alloc((size_t)T_TOK * HDIM * 2);
  int*   tidx   = (int*)  alloc((size_t)NFLAT * 4);
  float* tw     = (float*)alloc((size_t)NFLAT * 4);
  int*   rankb  = (int*)  alloc((size_t)NFLAT * 4);
  int*   counts = (int*)  alloc((size_t)NEXP * 4);
  int*   starts = (int*)  alloc((size_t)NEXP * 4);
  int*   rinfo  = (int*)  alloc((size_t)NFLAT * 4);
  float* wrow   = (float*)alloc((size_t)NFLAT * 4);
  unsigned short* a_buf = (unsigned short*)alloc((size_t)NFLAT * IDIM * 2);
  (void)ws_size; (void)in_sizes; (void)n_in; (void)out_size;

  hipMemsetAsync(d_out, 0, (size_t)T_TOK * HDIM * 4, stream);
  k_gating<<<T_TOK/16, 256, 0, stream>>>(hs, gw, hs_bf, tidx, tw);
  k_count_rank<<<NEXP, 64, 0, stream>>>(tidx, rankb, counts);
  k_build<<<1, 256, 0, stream>>>(tidx, tw, rankb, counts, starts, rinfo, wrow);
  k_gemm1<<<dim3(6, 4, NEXP), 256, 0, stream>>>(hs_bf, w13, counts, starts, rinfo, a_buf);
  k_gemm2<<<dim3(8, 4, NEXP), 256, 0, stream>>>(a_buf, w2, counts, starts, rinfo, wrow, out);
}

// Round 2
// 866.291 us; speedup vs baseline: 1.0793x; 1.0793x over previous
//
#include <hip/hip_runtime.h>
#include <hip/hip_bf16.h>

#define T_TOK 4096
#define HDIM  2048
#define NEXP  64
#define IDIM  768
#define TOPK  4
#define CAPE  512
#define NFLAT (T_TOK*TOPK)

typedef __bf16        bf16x8 __attribute__((ext_vector_type(8)));
typedef float         f32x4  __attribute__((ext_vector_type(4)));
typedef unsigned int  u32x4  __attribute__((ext_vector_type(4)));

__device__ __forceinline__ unsigned short f2bf(float f) {
  unsigned u = __builtin_bit_cast(unsigned, f);
  u = u + 0x7FFFu + ((u >> 16) & 1u);
  return (unsigned short)(u >> 16);
}
__device__ __forceinline__ unsigned pack2(float lo, float hi) {
  return (unsigned)f2bf(lo) | ((unsigned)f2bf(hi) << 16);
}

// ---------------- gating: logits, top-4, renorm weights; also hs -> bf16 ----------------
__global__ __launch_bounds__(256) void k_gating(
    const float* __restrict__ hs, const float* __restrict__ gw,
    unsigned short* __restrict__ hs_bf, int* __restrict__ tidx, float* __restrict__ tw)
{
  __shared__ float lg[16][64];
  const int tid = threadIdx.x;
  const int t0  = blockIdx.x * 16;

  // phase A: bf16 conversion of these 16 rows
  {
    const f32x4* src = (const f32x4*)(hs + (size_t)t0 * HDIM);
    for (int i = tid; i < 16 * HDIM / 4; i += 256) {
      f32x4 v = src[i];
      ushort4 o;
      o.x = f2bf(v[0]); o.y = f2bf(v[1]); o.z = f2bf(v[2]); o.w = f2bf(v[3]);
      *(ushort4*)(hs_bf + (size_t)t0 * HDIM + (size_t)i * 4) = o;
    }
  }

  // phase B: logits.  lane = expert, each wave handles 4 tokens.
  const int lane = tid & 63, wv = tid >> 6;
  {
    const f32x4* gr = (const f32x4*)(gw + (size_t)lane * HDIM);
    const f32x4* x0 = (const f32x4*)(hs + (size_t)(t0 + wv*4 + 0) * HDIM);
    const f32x4* x1 = (const f32x4*)(hs + (size_t)(t0 + wv*4 + 1) * HDIM);
    const f32x4* x2 = (const f32x4*)(hs + (size_t)(t0 + wv*4 + 2) * HDIM);
    const f32x4* x3 = (const f32x4*)(hs + (size_t)(t0 + wv*4 + 3) * HDIM);
    float a0=0.f, a1=0.f, a2=0.f, a3=0.f;
    for (int h = 0; h < HDIM/4; ++h) {
      f32x4 g = gr[h];
      f32x4 v0 = x0[h], v1 = x1[h], v2 = x2[h], v3 = x3[h];
      a0 += g[0]*v0[0] + g[1]*v0[1] + g[2]*v0[2] + g[3]*v0[3];
      a1 += g[0]*v1[0] + g[1]*v1[1] + g[2]*v1[2] + g[3]*v1[3];
      a2 += g[0]*v2[0] + g[1]*v2[1] + g[2]*v2[2] + g[3]*v2[3];
      a3 += g[0]*v3[0] + g[1]*v3[1] + g[2]*v3[2] + g[3]*v3[3];
    }
    lg[wv*4+0][lane] = a0;
    lg[wv*4+1][lane] = a1;
    lg[wv*4+2][lane] = a2;
    lg[wv*4+3][lane] = a3;
  }
  __syncthreads();

  // phase C: per-token top-4 (stable: strict >, lowest index wins) + softmax over selected
  if (tid < 16) {
    const int t = t0 + tid;
    unsigned long long chosen = 0ull;
    float bv[4]; int bi[4];
#pragma unroll
    for (int k = 0; k < 4; ++k) {
      float best = -1e30f; int b = 0;
      for (int e = 0; e < 64; ++e) {
        float v = lg[tid][e];
        if (!((chosen >> e) & 1ull) && v > best) { best = v; b = e; }
      }
      chosen |= 1ull << b; bv[k] = best; bi[k] = b;
    }
    float s = 0.f, w[4];
#pragma unroll
    for (int k = 0; k < 4; ++k) { w[k] = __expf(bv[k] - bv[0]); s += w[k]; }
    float inv = 1.f / s;
#pragma unroll
    for (int k = 0; k < 4; ++k) { tidx[t*4+k] = bi[k]; tw[t*4+k] = w[k] * inv; }
  }
}

// ---------------- per-expert stable rank (ballot scan) ----------------
__global__ __launch_bounds__(64) void k_count_rank(
    const int* __restrict__ tidx, int* __restrict__ rankb, int* __restrict__ counts)
{
  const int e = blockIdx.x;
  const int lane = threadIdx.x;
  int base = 0;
  for (int c = 0; c < NFLAT/64; ++c) {
    int n = c*64 + lane;
    bool m = (tidx[n] == e);
    unsigned long long mask = __ballot(m);
    if (m) rankb[n] = base + __popcll(mask & ((1ull << lane) - 1ull));
    base += __popcll(mask);
  }
  if (lane == 0) counts[e] = base;
}

// ---------------- starts scan + sorted-row maps ----------------
__global__ __launch_bounds__(256) void k_build(
    const int* __restrict__ tidx, const int* __restrict__ rankb,
    const int* __restrict__ counts,
    int* __restrict__ starts, int* __restrict__ row_info, int* __restrict__ sortpos)
{
  __shared__ int s_starts[NEXP];
  if (threadIdx.x == 0) {
    int s = 0;
    for (int e = 0; e < NEXP; ++e) { s_starts[e] = s; starts[e] = s; s += counts[e]; }
  }
  __syncthreads();
  for (int n = threadIdx.x; n < NFLAT; n += 256) {
    int e = tidx[n], r = rankb[n];
    int sr = s_starts[e] + r;           // unique per n, in [0, NFLAT)
    row_info[sr] = n;
    sortpos[n] = (r < CAPE) ? sr : -1;  // dropped rows contribute 0 at finalize
  }
}

// ---------------- GEMM1 (gather A) + fused SwiGLU -> a_buf (bf16) ----------------
// block tile: 128 rows x 128 i-cols, computing BOTH g and u halves.
__global__ __launch_bounds__(256, 2) void k_gemm1(
    const unsigned short* __restrict__ hs_bf, const float* __restrict__ w13,
    const int* __restrict__ counts, const int* __restrict__ starts,
    const int* __restrict__ row_info, unsigned short* __restrict__ a_buf)
{
  const int nt = blockIdx.x;   // 0..5   (128 i-cols each)
  const int mt = blockIdx.y;   // 0..3
  const int e  = blockIdx.z;   // 0..63
  const int count = min(counts[e], CAPE);
  const int R0 = mt * 128;
  if (R0 >= count) return;
  const int tid = threadIdx.x;
  const int base_sorted = starts[e] + R0;

  __shared__ __align__(16) char lds[3*16384];
  char* Alds = lds;             // [128 m][8 chunks of 16B], chunk xor-swizzled by (m&7)
  char* Bgl  = lds + 16384;    // [128 n][8 chunks], k-pair packed u32, swizzle (n&7)
  char* Bul  = lds + 32768;

  const int mrow = tid >> 3, cchunk = tid & 7;   // A staging coords
  int tokp[4];
#pragma unroll
  for (int p = 0; p < 4; ++p) {
    int sr = base_sorted + mrow + p*32;
    if (sr > NFLAT-1) sr = NFLAT-1;
    tokp[p] = row_info[sr] >> 2;
  }
  const float* w13e = w13 + (size_t)e * HDIM * (2*IDIM);
  const int kg = tid >> 5;          // 0..7  (k-group of 8)
  const int n4 = (tid & 31) * 4;    // 0..124

  const int lane = tid & 63, wv = tid >> 6;
  const int wr = wv >> 1, wc = wv & 1;

  f32x4 accg[4][4], accu[4][4];
#pragma unroll
  for (int i = 0; i < 4; ++i)
#pragma unroll
    for (int j = 0; j < 4; ++j) { accg[i][j] = f32x4{0.f,0.f,0.f,0.f}; accu[i][j] = f32x4{0.f,0.f,0.f,0.f}; }

  for (int kt = 0; kt < HDIM/64; ++kt) {
    // stage A (bf16 rows gathered by token)
#pragma unroll
    for (int p = 0; p < 4; ++p) {
      int m = mrow + p*32;
      u32x4 v = *(const u32x4*)(hs_bf + (size_t)tokp[p]*HDIM + kt*64 + cchunk*8);
      *(u32x4*)(Alds + m*128 + ((cchunk ^ (m & 7)) << 4)) = v;
    }
    // stage B: g half and u half, f32 -> bf16 k-pair packed
#pragma unroll
    for (int half = 0; half < 2; ++half) {
      const float* bp = w13e + (size_t)(kt*64 + kg*8) * (2*IDIM) + half*IDIM + nt*128 + n4;
      f32x4 f[8];
#pragma unroll
      for (int j = 0; j < 8; ++j) f[j] = *(const f32x4*)(bp + (size_t)j * (2*IDIM));
      char* Bl = half ? Bul : Bgl;
#pragma unroll
      for (int i = 0; i < 4; ++i) {
        int n = n4 + i;
        u32x4 q;
        q[0] = pack2(f[0][i], f[1][i]);
        q[1] = pack2(f[2][i], f[3][i]);
        q[2] = pack2(f[4][i], f[5][i]);
        q[3] = pack2(f[6][i], f[7][i]);
        *(u32x4*)(Bl + n*128 + ((kg ^ (n & 7)) << 4)) = q;
      }
    }
    __syncthreads();
    // compute
#pragma unroll
    for (int kfi = 0; kfi < 2; ++kfi) {
      bf16x8 af[4], bg[4], bu[4];
#pragma unroll
      for (int mi = 0; mi < 4; ++mi) {
        int row = wr*64 + mi*16 + (lane & 15);
        af[mi] = *(const bf16x8*)(Alds + row*128 + ((((kfi<<2)|(lane>>4)) ^ (row & 7)) << 4));
      }
#pragma unroll
      for (int ni = 0; ni < 4; ++ni) {
        int n = wc*64 + ni*16 + (lane & 15);
        int c = (((kfi<<2)|(lane>>4)) ^ (n & 7)) << 4;
        bg[ni] = *(const bf16x8*)(Bgl + n*128 + c);
        bu[ni] = *(const bf16x8*)(Bul + n*128 + c);
      }
#pragma unroll
      for (int mi = 0; mi < 4; ++mi)
#pragma unroll
        for (int ni = 0; ni < 4; ++ni) {
          accg[mi][ni] = __builtin_amdgcn_mfma_f32_16x16x32_bf16(af[mi], bg[ni], accg[mi][ni], 0, 0, 0);
          accu[mi][ni] = __builtin_amdgcn_mfma_f32_16x16x32_bf16(af[mi], bu[ni], accu[mi][ni], 0, 0, 0);
        }
    }
    __syncthreads();
  }

  // epilogue: silu(g)*u -> a_buf (bf16), rows are sorted-contiguous
#pragma unroll
  for (int mi = 0; mi < 4; ++mi) {
#pragma unroll
    for (int j = 0; j < 4; ++j) {
      int rl = wr*64 + mi*16 + (lane >> 4)*4 + j;
      if (R0 + rl < count) {
        size_t rowoff = (size_t)(base_sorted + rl) * IDIM;
#pragma unroll
        for (int ni = 0; ni < 4; ++ni) {
          int col = nt*128 + wc*64 + ni*16 + (lane & 15);
          float g = accg[mi][ni][j], u = accu[mi][ni][j];
          float a = (g / (1.f + __expf(-g))) * u;
          a_buf[rowoff + col] = f2bf(a);
        }
      }
    }
  }
}

// ---------------- GEMM2 -> y_buf (fp32, sorted rows, unweighted) ----------------
// block tile: 128 rows x 256 cols of H
__global__ __launch_bounds__(256, 2) void k_gemm2(
    const unsigned short* __restrict__ a_buf, const float* __restrict__ w2,
    const int* __restrict__ counts, const int* __restrict__ starts,
    float* __restrict__ y_buf)
{
  const int nt = blockIdx.x;   // 0..7  (256 cols each)
  const int mt = blockIdx.y;   // 0..3
  const int e  = blockIdx.z;   // 0..63
  const int count = min(counts[e], CAPE);
  const int R0 = mt * 128;
  if (R0 >= count) return;
  const int tid = threadIdx.x;
  const int base_sorted = starts[e] + R0;

  __shared__ __align__(16) char lds[16384 + 32768];
  char* Alds = lds;            // [128 m][8 chunks]
  char* Blds = lds + 16384;    // [256 n][8 chunks]

  const int mrow = tid >> 3, cchunk = tid & 7;
  int srp[4];
#pragma unroll
  for (int p = 0; p < 4; ++p) {
    int sr = base_sorted + mrow + p*32;
    srp[p] = (sr > NFLAT-1) ? (NFLAT-1) : sr;
  }
  const float* w2e = w2 + (size_t)e * IDIM * HDIM;
  const int kg = tid >> 5, n4 = (tid & 31) * 4;
  const int lane = tid & 63, wv = tid >> 6, wr = wv >> 1, wc = wv & 1;

  f32x4 acc[4][8];
#pragma unroll
  for (int i = 0; i < 4; ++i)
#pragma unroll
    for (int j = 0; j < 8; ++j) acc[i][j] = f32x4{0.f,0.f,0.f,0.f};

  for (int kt = 0; kt < IDIM/64; ++kt) {
    // stage A from a_buf (already bf16, rows contiguous in sorted space)
#pragma unroll
    for (int p = 0; p < 4; ++p) {
      int m = mrow + p*32;
      u32x4 v = *(const u32x4*)(a_buf + (size_t)srp[p]*IDIM + kt*64 + cchunk*8);
      *(u32x4*)(Alds + m*128 + ((cchunk ^ (m & 7)) << 4)) = v;
    }
    // stage B: 256 cols in two passes
#pragma unroll
    for (int pass = 0; pass < 2; ++pass) {
      int nn = n4 + pass*128;
      const float* bp = w2e + (size_t)(kt*64 + kg*8) * HDIM + nt*256 + nn;
      f32x4 f[8];
#pragma unroll
      for (int j = 0; j < 8; ++j) f[j] = *(const f32x4*)(bp + (size_t)j * HDIM);
#pragma unroll
      for (int i = 0; i < 4; ++i) {
        int n = nn + i;
        u32x4 q;
        q[0] = pack2(f[0][i], f[1][i]);
        q[1] = pack2(f[2][i], f[3][i]);
        q[2] = pack2(f[4][i], f[5][i]);
        q[3] = pack2(f[6][i], f[7][i]);
        *(u32x4*)(Blds + n*128 + ((kg ^ (n & 7)) << 4)) = q;
      }
    }
    __syncthreads();
#pragma unroll
    for (int kfi = 0; kfi < 2; ++kfi) {
      bf16x8 af[4], bb[8];
#pragma unroll
      for (int mi = 0; mi < 4; ++mi) {
        int row = wr*64 + mi*16 + (lane & 15);
        af[mi] = *(const bf16x8*)(Alds + row*128 + ((((kfi<<2)|(lane>>4)) ^ (row & 7)) << 4));
      }
#pragma unroll
      for (int ni = 0; ni < 8; ++ni) {
        int n = wc*128 + ni*16 + (lane & 15);
        bb[ni] = *(const bf16x8*)(Blds + n*128 + (((((kfi<<2)|(lane>>4)) ^ (n & 7))) << 4));
      }
#pragma unroll
      for (int mi = 0; mi < 4; ++mi)
#pragma unroll
        for (int ni = 0; ni < 8; ++ni)
          acc[mi][ni] = __builtin_amdgcn_mfma_f32_16x16x32_bf16(af[mi], bb[ni], acc[mi][ni], 0, 0, 0);
    }
    __syncthreads();
  }

  // epilogue: plain fp32 stores of unweighted y rows (sorted-contiguous)
#pragma unroll
  for (int mi = 0; mi < 4; ++mi) {
#pragma unroll
    for (int j = 0; j < 4; ++j) {
      int rl = wr*64 + mi*16 + (lane >> 4)*4 + j;
      if (R0 + rl < count) {
        int sr = base_sorted + rl;
        float* yrow = y_buf + (size_t)sr * HDIM;
#pragma unroll
        for (int ni = 0; ni < 8; ++ni) {
          int col = nt*256 + wc*128 + ni*16 + (lane & 15);
          yrow[col] = acc[mi][ni][j];
        }
      }
    }
  }
}

// ---------------- finalize: out[t] = sum_k tw[t,k] * y_buf[sortpos[t,k]] ----------------
__global__ __launch_bounds__(256) void k_finalize(
    const float* __restrict__ y_buf, const int* __restrict__ sortpos,
    const float* __restrict__ tw, float* __restrict__ out)
{
  const int t = blockIdx.x;
  const int tid = threadIdx.x;
  f32x4 acc0 = {0.f,0.f,0.f,0.f}, acc1 = {0.f,0.f,0.f,0.f};
#pragma unroll
  for (int k = 0; k < 4; ++k) {
    int sp = sortpos[t*4+k];
    float w = tw[t*4+k];
    if (sp >= 0) {
      const f32x4* yr = (const f32x4*)(y_buf + (size_t)sp * HDIM);
      acc0 += w * yr[tid];
      acc1 += w * yr[tid + 256];
    }
  }
  f32x4* o = (f32x4*)(out + (size_t)t * HDIM);
  o[tid] = acc0;
  o[tid + 256] = acc1;
}

extern "C" void kernel_launch(void* const* d_in, const int* in_sizes, int n_in,
                              void* d_out, int out_size, void* d_ws, size_t ws_size,
                              hipStream_t stream) {
  const float* hs  = (const float*)d_in[0];
  const float* gw  = (const float*)d_in[1];
  const float* w13 = (const float*)d_in[2];
  const float* w2  = (const float*)d_in[3];
  float* out = (float*)d_out;

  char* ws = (char*)d_ws;
  size_t off = 0;
  auto alloc = [&](size_t bytes) {
    off = (off + 255) & ~(size_t)255;
    char* p = ws + off;
    off += bytes;
    return p;
  };
  unsigned short* hs_bf = (unsigned short*)alloc((size_t)T_TOK * HDIM * 2);
  int*   tidx   = (int*)  alloc((size_t)NFLAT * 4);
  float* tw     = (float*)alloc((size_t)NFLAT * 4);
  int*   rankb  = (int*)  alloc((size_t)NFLAT * 4);
  int*   counts = (int*)  alloc((size_t)NEXP * 4);
  int*   starts = (int*)  alloc((size_t)NEXP * 4);
  int*   rinfo  = (int*)  alloc((size_t)NFLAT * 4);
  int*   sortp  = (int*)  alloc((size_t)NFLAT * 4);
  unsigned short* a_buf = (unsigned short*)alloc((size_t)NFLAT * IDIM * 2);
  float* y_buf  = (float*)alloc((size_t)NFLAT * HDIM * 4);
  (void)ws_size; (void)in_sizes; (void)n_in; (void)out_size;

  k_gating<<<T_TOK/16, 256, 0, stream>>>(hs, gw, hs_bf, tidx, tw);
  k_count_rank<<<NEXP, 64, 0, stream>>>(tidx, rankb, counts);
  k_build<<<1, 256, 0, stream>>>(tidx, rankb, counts, starts, rinfo, sortp);
  k_gemm1<<<dim3(6, 4, NEXP), 256, 0, stream>>>(hs_bf, w13, counts, starts, rinfo, a_buf);
  k_gemm2<<<dim3(8, 4, NEXP), 256, 0, stream>>>(a_buf, w2, counts, starts, y_buf);
  k_finalize<<<T_TOK, 256, 0, stream>>>(y_buf, sortp, tw, out);
}

// Round 3
// 796.692 us; speedup vs baseline: 1.1736x; 1.0874x over previous
//
#include <hip/hip_runtime.h>
#include <hip/hip_bf16.h>

#define T_TOK 4096
#define HDIM  2048
#define NEXP  64
#define IDIM  768
#define TOPK  4
#define CAPE  512
#define NFLAT (T_TOK*TOPK)

typedef __bf16        bf16x8 __attribute__((ext_vector_type(8)));
typedef float         f32x4  __attribute__((ext_vector_type(4)));
typedef unsigned int  u32x4  __attribute__((ext_vector_type(4)));

// native-cast based conversions (compiler emits v_cvt_pk_bf16_f32-class ops)
__device__ __forceinline__ unsigned short f2bf(float f) {
  __bf16 b = (__bf16)f;
  return __builtin_bit_cast(unsigned short, b);
}
__device__ __forceinline__ unsigned pack2(float lo, float hi) {
  return (unsigned)f2bf(lo) | ((unsigned)f2bf(hi) << 16);
}

// ---------------- gating: logits, top-4, renorm weights; also hs -> bf16 ----------------
__global__ __launch_bounds__(256) void k_gating(
    const float* __restrict__ hs, const float* __restrict__ gw,
    unsigned short* __restrict__ hs_bf, int* __restrict__ tidx, float* __restrict__ tw)
{
  __shared__ float lg[16][64];
  const int tid = threadIdx.x;
  const int t0  = blockIdx.x * 16;

  // phase A: bf16 conversion of these 16 rows
  {
    const f32x4* src = (const f32x4*)(hs + (size_t)t0 * HDIM);
    for (int i = tid; i < 16 * HDIM / 4; i += 256) {
      f32x4 v = src[i];
      ushort4 o;
      o.x = f2bf(v[0]); o.y = f2bf(v[1]); o.z = f2bf(v[2]); o.w = f2bf(v[3]);
      *(ushort4*)(hs_bf + (size_t)t0 * HDIM + (size_t)i * 4) = o;
    }
  }

  // phase B: logits.  lane = expert, each wave handles 4 tokens.
  const int lane = tid & 63, wv = tid >> 6;
  {
    const f32x4* gr = (const f32x4*)(gw + (size_t)lane * HDIM);
    const f32x4* x0 = (const f32x4*)(hs + (size_t)(t0 + wv*4 + 0) * HDIM);
    const f32x4* x1 = (const f32x4*)(hs + (size_t)(t0 + wv*4 + 1) * HDIM);
    const f32x4* x2 = (const f32x4*)(hs + (size_t)(t0 + wv*4 + 2) * HDIM);
    const f32x4* x3 = (const f32x4*)(hs + (size_t)(t0 + wv*4 + 3) * HDIM);
    float a0=0.f, a1=0.f, a2=0.f, a3=0.f;
    for (int h = 0; h < HDIM/4; ++h) {
      f32x4 g = gr[h];
      f32x4 v0 = x0[h], v1 = x1[h], v2 = x2[h], v3 = x3[h];
      a0 += g[0]*v0[0] + g[1]*v0[1] + g[2]*v0[2] + g[3]*v0[3];
      a1 += g[0]*v1[0] + g[1]*v1[1] + g[2]*v1[2] + g[3]*v1[3];
      a2 += g[0]*v2[0] + g[1]*v2[1] + g[2]*v2[2] + g[3]*v2[3];
      a3 += g[0]*v3[0] + g[1]*v3[1] + g[2]*v3[2] + g[3]*v3[3];
    }
    lg[wv*4+0][lane] = a0;
    lg[wv*4+1][lane] = a1;
    lg[wv*4+2][lane] = a2;
    lg[wv*4+3][lane] = a3;
  }
  __syncthreads();

  // phase C: per-token top-4 (stable: strict >, lowest index wins) + softmax over selected
  if (tid < 16) {
    const int t = t0 + tid;
    unsigned long long chosen = 0ull;
    float bv[4]; int bi[4];
#pragma unroll
    for (int k = 0; k < 4; ++k) {
      float best = -1e30f; int b = 0;
      for (int e = 0; e < 64; ++e) {
        float v = lg[tid][e];
        if (!((chosen >> e) & 1ull) && v > best) { best = v; b = e; }
      }
      chosen |= 1ull << b; bv[k] = best; bi[k] = b;
    }
    float s = 0.f, w[4];
#pragma unroll
    for (int k = 0; k < 4; ++k) { w[k] = __expf(bv[k] - bv[0]); s += w[k]; }
    float inv = 1.f / s;
#pragma unroll
    for (int k = 0; k < 4; ++k) { tidx[t*4+k] = bi[k]; tw[t*4+k] = w[k] * inv; }
  }
}

// ---------------- per-expert stable rank (ballot scan) ----------------
__global__ __launch_bounds__(64) void k_count_rank(
    const int* __restrict__ tidx, int* __restrict__ rankb, int* __restrict__ counts)
{
  const int e = blockIdx.x;
  const int lane = threadIdx.x;
  int base = 0;
  for (int c = 0; c < NFLAT/64; ++c) {
    int n = c*64 + lane;
    bool m = (tidx[n] == e);
    unsigned long long mask = __ballot(m);
    if (m) rankb[n] = base + __popcll(mask & ((1ull << lane) - 1ull));
    base += __popcll(mask);
  }
  if (lane == 0) counts[e] = base;
}

// ---------------- starts scan + sorted-row maps ----------------
__global__ __launch_bounds__(256) void k_build(
    const int* __restrict__ tidx, const int* __restrict__ rankb,
    const int* __restrict__ counts,
    int* __restrict__ starts, int* __restrict__ row_info, int* __restrict__ sortpos)
{
  __shared__ int s_starts[NEXP];
  if (threadIdx.x == 0) {
    int s = 0;
    for (int e = 0; e < NEXP; ++e) { s_starts[e] = s; starts[e] = s; s += counts[e]; }
  }
  __syncthreads();
  for (int n = threadIdx.x; n < NFLAT; n += 256) {
    int e = tidx[n], r = rankb[n];
    int sr = s_starts[e] + r;           // unique per n, in [0, NFLAT)
    row_info[sr] = n;
    sortpos[n] = (r < CAPE) ? sr : -1;  // dropped rows contribute 0 at finalize
  }
}

// ---------------- GEMM1 (gather A) + fused SwiGLU -> a_buf (bf16) ----------------
// BM=256 rows x BN=128 i-cols (both g and u halves), BK=64, 512 threads / 8 waves.
__global__ __launch_bounds__(512, 2) void k_gemm1(
    const unsigned short* __restrict__ hs_bf, const float* __restrict__ w13,
    const int* __restrict__ counts, const int* __restrict__ starts,
    const int* __restrict__ row_info, unsigned short* __restrict__ a_buf)
{
  const int nt = blockIdx.x;   // 0..5   (128 i-cols each)
  const int mt = blockIdx.y;   // 0..1   (256 rows each)
  const int e  = blockIdx.z;   // 0..63
  const int count = min(counts[e], CAPE);
  const int R0 = mt * 256;
  if (R0 >= count) return;
  const int tid = threadIdx.x;
  const int base_sorted = starts[e] + R0;

  __shared__ __align__(16) char lds[2*32768];
  char* Alds = lds;             // [256 m][8 chunks of 16B], chunk xor-swizzled by (m&7)
  char* Bgl  = lds + 32768;    // [128 n][8 chunks], k-pair packed u32, swizzle (n&7)
  char* Bul  = lds + 32768 + 16384;

  // A staging coords: 4 rows per thread (stride 64)
  const int mrow = tid >> 3, cchunk = tid & 7;
  int tokp[4];
#pragma unroll
  for (int p = 0; p < 4; ++p) {
    int sr = base_sorted + mrow + p*64;
    if (sr > NFLAT-1) sr = NFLAT-1;
    tokp[p] = row_info[sr] >> 2;
  }
  const float* w13e = w13 + (size_t)e * HDIM * (2*IDIM);
  // B staging coords: half from tid>>8, within-half 256 threads cover 128 cols x 64 k
  const int half = tid >> 8;       // 0..1
  const int t8   = tid & 255;
  const int kg   = t8 >> 5;        // 0..7 (k-group of 8)
  const int n4   = (t8 & 31) * 4;  // 0..124

  const int lane = tid & 63, wv = tid >> 6;
  const int wr = wv >> 1, wc = wv & 1;   // 4M x 2N wave grid, wave tile 64x64 per half

  f32x4 accg[4][4], accu[4][4];
#pragma unroll
  for (int i = 0; i < 4; ++i)
#pragma unroll
    for (int j = 0; j < 4; ++j) { accg[i][j] = f32x4{0.f,0.f,0.f,0.f}; accu[i][j] = f32x4{0.f,0.f,0.f,0.f}; }

  for (int kt = 0; kt < HDIM/64; ++kt) {
    // stage A (bf16 rows gathered by token): 256 rows x 64 k
#pragma unroll
    for (int p = 0; p < 4; ++p) {
      int m = mrow + p*64;
      u32x4 v = *(const u32x4*)(hs_bf + (size_t)tokp[p]*HDIM + kt*64 + cchunk*8);
      *(u32x4*)(Alds + m*128 + ((cchunk ^ (m & 7)) << 4)) = v;
    }
    // stage B: this thread's half, f32 -> bf16 k-pair packed
    {
      const float* bp = w13e + (size_t)(kt*64 + kg*8) * (2*IDIM) + half*IDIM + nt*128 + n4;
      f32x4 f[8];
#pragma unroll
      for (int j = 0; j < 8; ++j) f[j] = *(const f32x4*)(bp + (size_t)j * (2*IDIM));
      char* Bl = half ? Bul : Bgl;
#pragma unroll
      for (int i = 0; i < 4; ++i) {
        int n = n4 + i;
        u32x4 q;
        q[0] = pack2(f[0][i], f[1][i]);
        q[1] = pack2(f[2][i], f[3][i]);
        q[2] = pack2(f[4][i], f[5][i]);
        q[3] = pack2(f[6][i], f[7][i]);
        *(u32x4*)(Bl + n*128 + ((kg ^ (n & 7)) << 4)) = q;
      }
    }
    __syncthreads();
    // compute
#pragma unroll
    for (int kfi = 0; kfi < 2; ++kfi) {
      bf16x8 af[4], bg[4], bu[4];
#pragma unroll
      for (int mi = 0; mi < 4; ++mi) {
        int row = wr*64 + mi*16 + (lane & 15);
        af[mi] = *(const bf16x8*)(Alds + row*128 + ((((kfi<<2)|(lane>>4)) ^ (row & 7)) << 4));
      }
#pragma unroll
      for (int ni = 0; ni < 4; ++ni) {
        int n = wc*64 + ni*16 + (lane & 15);
        int c = (((kfi<<2)|(lane>>4)) ^ (n & 7)) << 4;
        bg[ni] = *(const bf16x8*)(Bgl + n*128 + c);
        bu[ni] = *(const bf16x8*)(Bul + n*128 + c);
      }
#pragma unroll
      for (int mi = 0; mi < 4; ++mi)
#pragma unroll
        for (int ni = 0; ni < 4; ++ni) {
          accg[mi][ni] = __builtin_amdgcn_mfma_f32_16x16x32_bf16(af[mi], bg[ni], accg[mi][ni], 0, 0, 0);
          accu[mi][ni] = __builtin_amdgcn_mfma_f32_16x16x32_bf16(af[mi], bu[ni], accu[mi][ni], 0, 0, 0);
        }
    }
    __syncthreads();
  }

  // epilogue: silu(g)*u -> a_buf (bf16), rows are sorted-contiguous
#pragma unroll
  for (int mi = 0; mi < 4; ++mi) {
#pragma unroll
    for (int j = 0; j < 4; ++j) {
      int rl = wr*64 + mi*16 + (lane >> 4)*4 + j;
      if (R0 + rl < count) {
        size_t rowoff = (size_t)(base_sorted + rl) * IDIM;
#pragma unroll
        for (int ni = 0; ni < 4; ++ni) {
          int col = nt*128 + wc*64 + ni*16 + (lane & 15);
          float g = accg[mi][ni][j], u = accu[mi][ni][j];
          float a = (g / (1.f + __expf(-g))) * u;
          a_buf[rowoff + col] = f2bf(a);
        }
      }
    }
  }
}

// ---------------- GEMM2 -> y_buf (fp32, sorted rows, unweighted) ----------------
// BM=256 rows x BN=256 cols of H, BK=64, 512 threads / 8 waves.
__global__ __launch_bounds__(512, 2) void k_gemm2(
    const unsigned short* __restrict__ a_buf, const float* __restrict__ w2,
    const int* __restrict__ counts, const int* __restrict__ starts,
    float* __restrict__ y_buf)
{
  const int nt = blockIdx.x;   // 0..7  (256 cols each)
  const int mt = blockIdx.y;   // 0..1  (256 rows each)
  const int e  = blockIdx.z;   // 0..63
  const int count = min(counts[e], CAPE);
  const int R0 = mt * 256;
  if (R0 >= count) return;
  const int tid = threadIdx.x;
  const int base_sorted = starts[e] + R0;

  __shared__ __align__(16) char lds[32768 + 32768];
  char* Alds = lds;            // [256 m][8 chunks]
  char* Blds = lds + 32768;    // [256 n][8 chunks]

  const int mrow = tid >> 3, cchunk = tid & 7;
  int srp[4];
#pragma unroll
  for (int p = 0; p < 4; ++p) {
    int sr = base_sorted + mrow + p*64;
    srp[p] = (sr > NFLAT-1) ? (NFLAT-1) : sr;
  }
  const float* w2e = w2 + (size_t)e * IDIM * HDIM;
  const int pass = tid >> 8;        // which 128-col group of B this thread stages
  const int t8   = tid & 255;
  const int kg   = t8 >> 5, n4 = (t8 & 31) * 4;
  const int lane = tid & 63, wv = tid >> 6, wr = wv >> 1, wc = wv & 1;

  f32x4 acc[4][8];
#pragma unroll
  for (int i = 0; i < 4; ++i)
#pragma unroll
    for (int j = 0; j < 8; ++j) acc[i][j] = f32x4{0.f,0.f,0.f,0.f};

  for (int kt = 0; kt < IDIM/64; ++kt) {
    // stage A from a_buf (already bf16, rows contiguous in sorted space)
#pragma unroll
    for (int p = 0; p < 4; ++p) {
      int m = mrow + p*64;
      u32x4 v = *(const u32x4*)(a_buf + (size_t)srp[p]*IDIM + kt*64 + cchunk*8);
      *(u32x4*)(Alds + m*128 + ((cchunk ^ (m & 7)) << 4)) = v;
    }
    // stage B: 256 cols, this thread's 128-col group
    {
      int nn = n4 + pass*128;
      const float* bp = w2e + (size_t)(kt*64 + kg*8) * HDIM + nt*256 + nn;
      f32x4 f[8];
#pragma unroll
      for (int j = 0; j < 8; ++j) f[j] = *(const f32x4*)(bp + (size_t)j * HDIM);
#pragma unroll
      for (int i = 0; i < 4; ++i) {
        int n = nn + i;
        u32x4 q;
        q[0] = pack2(f[0][i], f[1][i]);
        q[1] = pack2(f[2][i], f[3][i]);
        q[2] = pack2(f[4][i], f[5][i]);
        q[3] = pack2(f[6][i], f[7][i]);
        *(u32x4*)(Blds + n*128 + ((kg ^ (n & 7)) << 4)) = q;
      }
    }
    __syncthreads();
#pragma unroll
    for (int kfi = 0; kfi < 2; ++kfi) {
      bf16x8 af[4], bb[8];
#pragma unroll
      for (int mi = 0; mi < 4; ++mi) {
        int row = wr*64 + mi*16 + (lane & 15);
        af[mi] = *(const bf16x8*)(Alds + row*128 + ((((kfi<<2)|(lane>>4)) ^ (row & 7)) << 4));
      }
#pragma unroll
      for (int ni = 0; ni < 8; ++ni) {
        int n = wc*128 + ni*16 + (lane & 15);
        bb[ni] = *(const bf16x8*)(Blds + n*128 + (((((kfi<<2)|(lane>>4)) ^ (n & 7))) << 4));
      }
#pragma unroll
      for (int mi = 0; mi < 4; ++mi)
#pragma unroll
        for (int ni = 0; ni < 8; ++ni)
          acc[mi][ni] = __builtin_amdgcn_mfma_f32_16x16x32_bf16(af[mi], bb[ni], acc[mi][ni], 0, 0, 0);
    }
    __syncthreads();
  }

  // epilogue: plain fp32 stores of unweighted y rows (sorted-contiguous)
#pragma unroll
  for (int mi = 0; mi < 4; ++mi) {
#pragma unroll
    for (int j = 0; j < 4; ++j) {
      int rl = wr*64 + mi*16 + (lane >> 4)*4 + j;
      if (R0 + rl < count) {
        int sr = base_sorted + rl;
        float* yrow = y_buf + (size_t)sr * HDIM;
#pragma unroll
        for (int ni = 0; ni < 8; ++ni) {
          int col = nt*256 + wc*128 + ni*16 + (lane & 15);
          yrow[col] = acc[mi][ni][j];
        }
      }
    }
  }
}

// ---------------- finalize: out[t] = sum_k tw[t,k] * y_buf[sortpos[t,k]] ----------------
__global__ __launch_bounds__(256) void k_finalize(
    const float* __restrict__ y_buf, const int* __restrict__ sortpos,
    const float* __restrict__ tw, float* __restrict__ out)
{
  const int t = blockIdx.x;
  const int tid = threadIdx.x;
  f32x4 acc0 = {0.f,0.f,0.f,0.f}, acc1 = {0.f,0.f,0.f,0.f};
#pragma unroll
  for (int k = 0; k < 4; ++k) {
    int sp = sortpos[t*4+k];
    float w = tw[t*4+k];
    if (sp >= 0) {
      const f32x4* yr = (const f32x4*)(y_buf + (size_t)sp * HDIM);
      acc0 += w * yr[tid];
      acc1 += w * yr[tid + 256];
    }
  }
  f32x4* o = (f32x4*)(out + (size_t)t * HDIM);
  o[tid] = acc0;
  o[tid + 256] = acc1;
}

extern "C" void kernel_launch(void* const* d_in, const int* in_sizes, int n_in,
                              void* d_out, int out_size, void* d_ws, size_t ws_size,
                              hipStream_t stream) {
  const float* hs  = (const float*)d_in[0];
  const float* gw  = (const float*)d_in[1];
  const float* w13 = (const float*)d_in[2];
  const float* w2  = (const float*)d_in[3];
  float* out = (float*)d_out;

  char* ws = (char*)d_ws;
  size_t off = 0;
  auto alloc = [&](size_t bytes) {
    off = (off + 255) & ~(size_t)255;
    char* p = ws + off;
    off += bytes;
    return p;
  };
  unsigned short* hs_bf = (unsigned short*)alloc((size_t)T_TOK * HDIM * 2);
  int*   tidx   = (int*)  alloc((size_t)NFLAT * 4);
  float* tw     = (float*)alloc((size_t)NFLAT * 4);
  int*   rankb  = (int*)  alloc((size_t)NFLAT * 4);
  int*   counts = (int*)  alloc((size_t)NEXP * 4);
  int*   starts = (int*)  alloc((size_t)NEXP * 4);
  int*   rinfo  = (int*)  alloc((size_t)NFLAT * 4);
  int*   sortp  = (int*)  alloc((size_t)NFLAT * 4);
  unsigned short* a_buf = (unsigned short*)alloc((size_t)NFLAT * IDIM * 2);
  float* y_buf  = (float*)alloc((size_t)NFLAT * HDIM * 4);
  (void)ws_size; (void)in_sizes; (void)n_in; (void)out_size;

  k_gating<<<T_TOK/16, 256, 0, stream>>>(hs, gw, hs_bf, tidx, tw);
  k_count_rank<<<NEXP, 64, 0, stream>>>(tidx, rankb, counts);
  k_build<<<1, 256, 0, stream>>>(tidx, rankb, counts, starts, rinfo, sortp);
  k_gemm1<<<dim3(6, 2, NEXP), 512, 0, stream>>>(hs_bf, w13, counts, starts, rinfo, a_buf);
  k_gemm2<<<dim3(8, 2, NEXP), 512, 0, stream>>>(a_buf, w2, counts, starts, y_buf);
  k_finalize<<<T_TOK, 256, 0, stream>>>(y_buf, sortp, tw, out);
}